// Round 3
// baseline (54.587 us; speedup 1.0000x reference)
//
#include <hip/hip_runtime.h>

// DiversityLoss: attention_maps [B=64, M=32, H*W=16384] fp32.
// gram[b,i,j] = sum_k (A[b,i,k]^2 * A[b,j,k]^2); loss = mean_b sum_{i<j} relu(0.1-gram)/496.
//
// HBM floor: 134 MB / ~7 TB/s ~= 19-21 us.
// R1 (4x4 tiles, 4 blk/CU): 44.7 us. R2 (8x8 tiles, 2 blk/CU): 48.1 us -- occupancy
// loss beat the LDS savings. R3: 8x8 tiles AND 4 blk/CU (NC=16, TS=128, 18 KiB LDS,
// VGPR<=128 via launch_bounds(256,4)) so HBM/LDS/VALU pipes overlap across 16 waves/CU.

#define MARGIN 0.1f

constexpr int B_ = 64;
constexpr int M_ = 32;
constexpr int K_ = 16384;
constexpr int NC = 16;           // chunks per batch -> grid 1024 = 4 blocks/CU
constexpr int KC = K_ / NC;      // 1024
constexpr int TS = 128;          // k per LDS subtile -> 18 KiB staging
constexpr int NSUB = KC / TS;    // 8
constexpr int LST = 36;          // dwords per k-row (32 + 4 pad)

__global__ __launch_bounds__(256, 4) void gram_partial(const float* __restrict__ A,
                                                       float* __restrict__ ws_g) {
  __shared__ float lds[TS * LST];  // 18 KiB (also reused for 16 KiB epilogue reduce)

  const int tid  = threadIdx.x;
  const int w    = tid >> 6;       // wave 0..3
  const int lane = tid & 63;

  const int b = blockIdx.x >> 4;   // batch
  const int c = blockIdx.x & (NC - 1);

  // --- staging coords: thread loads 4 rows x (2k x 2 u-slices), transposed ---
  const int h  = lane >> 5;        // 0/1
  const int kl = lane & 31;        // k-pair lane 0..31
  const int r0 = (w * 2 + h) * 4;  // row-quad base: 0,4,...,28

  // --- compute coords: 16 lanes cover 32x32 gram as 4x4 grid of 8x8 tiles; 4 k-groups ---
  const int g   = lane >> 4;       // k-group 0..3
  const int lid = lane & 15;
  const int tr  = lid >> 2;        // tile row 0..3
  const int tc  = lid & 3;         // tile col 0..3

  const float2* A2 = reinterpret_cast<const float2*>(A);
  const size_t rowstride2 = K_ / 2;  // 8192
  const size_t base2 = (size_t)(b * M_ + r0) * rowstride2 + (size_t)c * (KC / 2) + kl;

  float2 v[2][4];  // [u][row-in-quad] -- 16 VGPRs held across compute

  // prologue: load + stage subtile 0
#pragma unroll
  for (int u = 0; u < 2; ++u)
#pragma unroll
    for (int i = 0; i < 4; ++i)
      v[u][i] = A2[base2 + (size_t)i * rowstride2 + u * 32];

#pragma unroll
  for (int u = 0; u < 2; ++u) {
    const int k0 = u * 64 + kl * 2;
    float4 q0, q1;
    q0.x = v[u][0].x * v[u][0].x; q0.y = v[u][1].x * v[u][1].x;
    q0.z = v[u][2].x * v[u][2].x; q0.w = v[u][3].x * v[u][3].x;
    q1.x = v[u][0].y * v[u][0].y; q1.y = v[u][1].y * v[u][1].y;
    q1.z = v[u][2].y * v[u][2].y; q1.w = v[u][3].y * v[u][3].y;
    *reinterpret_cast<float4*>(&lds[(k0 + 0) * LST + r0]) = q0;
    *reinterpret_cast<float4*>(&lds[(k0 + 1) * LST + r0]) = q1;
  }
  __syncthreads();

  float acc[8][8];
#pragma unroll
  for (int p = 0; p < 8; ++p)
#pragma unroll
    for (int q = 0; q < 8; ++q) acc[p][q] = 0.0f;

  const float4* L4 = reinterpret_cast<const float4*>(lds);

  for (int s = 0; s < NSUB; ++s) {
    // prefetch next subtile into registers (flies under the compute below)
    if (s + 1 < NSUB) {
#pragma unroll
      for (int u = 0; u < 2; ++u)
#pragma unroll
        for (int i = 0; i < 4; ++i)
          v[u][i] = A2[base2 + (size_t)i * rowstride2 + (s + 1) * (TS / 2) + u * 32];
    }

    // compute: wave w owns k in [w*32, w*32+32); group g takes k = base+it*4+g
#pragma unroll 4
    for (int it = 0; it < 8; ++it) {
      const int k = w * 32 + it * 4 + g;
      const float4* Lk = L4 + k * (LST / 4);
      const float4 a0 = Lk[tr * 2];
      const float4 a1 = Lk[tr * 2 + 1];
      const float4 b0 = Lk[tc * 2];
      const float4 b1 = Lk[tc * 2 + 1];
      acc[0][0] = fmaf(a0.x, b0.x, acc[0][0]); acc[0][1] = fmaf(a0.x, b0.y, acc[0][1]);
      acc[0][2] = fmaf(a0.x, b0.z, acc[0][2]); acc[0][3] = fmaf(a0.x, b0.w, acc[0][3]);
      acc[0][4] = fmaf(a0.x, b1.x, acc[0][4]); acc[0][5] = fmaf(a0.x, b1.y, acc[0][5]);
      acc[0][6] = fmaf(a0.x, b1.z, acc[0][6]); acc[0][7] = fmaf(a0.x, b1.w, acc[0][7]);
      acc[1][0] = fmaf(a0.y, b0.x, acc[1][0]); acc[1][1] = fmaf(a0.y, b0.y, acc[1][1]);
      acc[1][2] = fmaf(a0.y, b0.z, acc[1][2]); acc[1][3] = fmaf(a0.y, b0.w, acc[1][3]);
      acc[1][4] = fmaf(a0.y, b1.x, acc[1][4]); acc[1][5] = fmaf(a0.y, b1.y, acc[1][5]);
      acc[1][6] = fmaf(a0.y, b1.z, acc[1][6]); acc[1][7] = fmaf(a0.y, b1.w, acc[1][7]);
      acc[2][0] = fmaf(a0.z, b0.x, acc[2][0]); acc[2][1] = fmaf(a0.z, b0.y, acc[2][1]);
      acc[2][2] = fmaf(a0.z, b0.z, acc[2][2]); acc[2][3] = fmaf(a0.z, b0.w, acc[2][3]);
      acc[2][4] = fmaf(a0.z, b1.x, acc[2][4]); acc[2][5] = fmaf(a0.z, b1.y, acc[2][5]);
      acc[2][6] = fmaf(a0.z, b1.z, acc[2][6]); acc[2][7] = fmaf(a0.z, b1.w, acc[2][7]);
      acc[3][0] = fmaf(a0.w, b0.x, acc[3][0]); acc[3][1] = fmaf(a0.w, b0.y, acc[3][1]);
      acc[3][2] = fmaf(a0.w, b0.z, acc[3][2]); acc[3][3] = fmaf(a0.w, b0.w, acc[3][3]);
      acc[3][4] = fmaf(a0.w, b1.x, acc[3][4]); acc[3][5] = fmaf(a0.w, b1.y, acc[3][5]);
      acc[3][6] = fmaf(a0.w, b1.z, acc[3][6]); acc[3][7] = fmaf(a0.w, b1.w, acc[3][7]);
      acc[4][0] = fmaf(a1.x, b0.x, acc[4][0]); acc[4][1] = fmaf(a1.x, b0.y, acc[4][1]);
      acc[4][2] = fmaf(a1.x, b0.z, acc[4][2]); acc[4][3] = fmaf(a1.x, b0.w, acc[4][3]);
      acc[4][4] = fmaf(a1.x, b1.x, acc[4][4]); acc[4][5] = fmaf(a1.x, b1.y, acc[4][5]);
      acc[4][6] = fmaf(a1.x, b1.z, acc[4][6]); acc[4][7] = fmaf(a1.x, b1.w, acc[4][7]);
      acc[5][0] = fmaf(a1.y, b0.x, acc[5][0]); acc[5][1] = fmaf(a1.y, b0.y, acc[5][1]);
      acc[5][2] = fmaf(a1.y, b0.z, acc[5][2]); acc[5][3] = fmaf(a1.y, b0.w, acc[5][3]);
      acc[5][4] = fmaf(a1.y, b1.x, acc[5][4]); acc[5][5] = fmaf(a1.y, b1.y, acc[5][5]);
      acc[5][6] = fmaf(a1.y, b1.z, acc[5][6]); acc[5][7] = fmaf(a1.y, b1.w, acc[5][7]);
      acc[6][0] = fmaf(a1.z, b0.x, acc[6][0]); acc[6][1] = fmaf(a1.z, b0.y, acc[6][1]);
      acc[6][2] = fmaf(a1.z, b0.z, acc[6][2]); acc[6][3] = fmaf(a1.z, b0.w, acc[6][3]);
      acc[6][4] = fmaf(a1.z, b1.x, acc[6][4]); acc[6][5] = fmaf(a1.z, b1.y, acc[6][5]);
      acc[6][6] = fmaf(a1.z, b1.z, acc[6][6]); acc[6][7] = fmaf(a1.z, b1.w, acc[6][7]);
      acc[7][0] = fmaf(a1.w, b0.x, acc[7][0]); acc[7][1] = fmaf(a1.w, b0.y, acc[7][1]);
      acc[7][2] = fmaf(a1.w, b0.z, acc[7][2]); acc[7][3] = fmaf(a1.w, b0.w, acc[7][3]);
      acc[7][4] = fmaf(a1.w, b1.x, acc[7][4]); acc[7][5] = fmaf(a1.w, b1.y, acc[7][5]);
      acc[7][6] = fmaf(a1.w, b1.z, acc[7][6]); acc[7][7] = fmaf(a1.w, b1.w, acc[7][7]);
    }

    if (s + 1 < NSUB) {
      __syncthreads();  // everyone done reading this subtile
#pragma unroll
      for (int u = 0; u < 2; ++u) {
        const int k0 = u * 64 + kl * 2;
        float4 q0, q1;
        q0.x = v[u][0].x * v[u][0].x; q0.y = v[u][1].x * v[u][1].x;
        q0.z = v[u][2].x * v[u][2].x; q0.w = v[u][3].x * v[u][3].x;
        q1.x = v[u][0].y * v[u][0].y; q1.y = v[u][1].y * v[u][1].y;
        q1.z = v[u][2].y * v[u][2].y; q1.w = v[u][3].y * v[u][3].y;
        *reinterpret_cast<float4*>(&lds[(k0 + 0) * LST + r0]) = q0;
        *reinterpret_cast<float4*>(&lds[(k0 + 1) * LST + r0]) = q1;
      }
      __syncthreads();  // staged data visible
    }
  }

  // reduce k-group partials across lanes (xor 16, then 32)
#pragma unroll
  for (int p = 0; p < 8; ++p)
#pragma unroll
    for (int q = 0; q < 8; ++q) {
      float t = acc[p][q];
      t += __shfl_xor(t, 16);
      t += __shfl_xor(t, 32);
      acc[p][q] = t;
    }

  __syncthreads();  // staging buffer now dead; reuse for cross-wave reduction

  if (g == 0) {
#pragma unroll
    for (int p = 0; p < 8; ++p) {
      const int off = w * 1024 + (tr * 8 + p) * 32 + tc * 8;
      float4 lo, hi;
      lo.x = acc[p][0]; lo.y = acc[p][1]; lo.z = acc[p][2]; lo.w = acc[p][3];
      hi.x = acc[p][4]; hi.y = acc[p][5]; hi.z = acc[p][6]; hi.w = acc[p][7];
      *reinterpret_cast<float4*>(&lds[off]) = lo;
      *reinterpret_cast<float4*>(&lds[off + 4]) = hi;
    }
  }
  __syncthreads();

  const float4 s0 = L4[tid];
  const float4 s1 = L4[256 + tid];
  const float4 s2 = L4[512 + tid];
  const float4 s3 = L4[768 + tid];
  float4 o;
  o.x = s0.x + s1.x + s2.x + s3.x;
  o.y = s0.y + s1.y + s2.y + s3.y;
  o.z = s0.z + s1.z + s2.z + s3.z;
  o.w = s0.w + s1.w + s2.w + s3.w;
  reinterpret_cast<float4*>(ws_g)[(size_t)blockIdx.x * 256 + tid] = o;
}

// Kernel 2: per-batch -> sum chunk partials, relu margin, strict upper triangle.
__global__ __launch_bounds__(256) void reduce_batch(const float* __restrict__ ws_g,
                                                    float* __restrict__ ws_b) {
  const int b   = blockIdx.x;
  const int tid = threadIdx.x;
  const float4* G4 = reinterpret_cast<const float4*>(ws_g);

  float4 s = make_float4(0.f, 0.f, 0.f, 0.f);
#pragma unroll
  for (int c = 0; c < NC; ++c) {
    const float4 t = G4[((size_t)(b * NC + c)) * 256 + tid];
    s.x += t.x; s.y += t.y; s.z += t.z; s.w += t.w;
  }
  const float gv[4] = {s.x, s.y, s.z, s.w};
  float local = 0.f;
#pragma unroll
  for (int e = 0; e < 4; ++e) {
    const int idx = tid * 4 + e;
    const int ii = idx >> 5;
    const int jj = idx & 31;
    if (jj > ii) local += fmaxf(MARGIN - gv[e], 0.0f);
  }

  float vv = local;
#pragma unroll
  for (int off = 32; off > 0; off >>= 1) vv += __shfl_down(vv, off);
  __shared__ float red[4];
  if ((tid & 63) == 0) red[tid >> 6] = vv;
  __syncthreads();
  if (tid == 0) ws_b[b] = (red[0] + red[1] + red[2] + red[3]) * (1.0f / 496.0f);
}

// Kernel 3: mean over batches.
__global__ void final_mean(const float* __restrict__ ws_b, float* __restrict__ out) {
  float v = ws_b[threadIdx.x];  // 64 threads
#pragma unroll
  for (int off = 32; off > 0; off >>= 1) v += __shfl_down(v, off);
  if (threadIdx.x == 0) out[0] = v * (1.0f / 64.0f);
}

extern "C" void kernel_launch(void* const* d_in, const int* in_sizes, int n_in,
                              void* d_out, int out_size, void* d_ws, size_t ws_size,
                              hipStream_t stream) {
  const float* A = reinterpret_cast<const float*>(d_in[0]);
  float* out = reinterpret_cast<float*>(d_out);

  // ws: [1024 blocks][1024 floats] partial grams (4 MiB) + [64] per-batch losses
  float* ws_g = reinterpret_cast<float*>(d_ws);
  float* ws_b = ws_g + (size_t)B_ * NC * M_ * M_;

  gram_partial<<<B_ * NC, 256, 0, stream>>>(A, ws_g);
  reduce_batch<<<B_, 256, 0, stream>>>(ws_g, ws_b);
  final_mean<<<1, 64, 0, stream>>>(ws_b, out);
}

// Round 4
// 46.504 us; speedup vs baseline: 1.1738x; 1.1738x over previous
//
#include <hip/hip_runtime.h>
#include <hip/hip_bf16.h>

// DiversityLoss: attention_maps [B=64, M=32, H*W=16384] fp32.
// gram[b,i,j] = sum_k (A[b,i,k]^2 * A[b,j,k]^2); loss = mean_b sum_{i<j} relu(0.1-gram)/496.
//
// R1-R3 (fp32 VALU + LDS tiles): 44.7 / 48.1 / 54.6 us -- LDS-issue-bound, then
// occupancy-bound, then VGPR-spill-bound. R4: bf16 MFMA, zero LDS in main loop.
// Key trick: for S*S^T with M=32, the mfma_f32_32x32x16_bf16 A-frag and B-frag are
// the SAME register (lane l holds S[l&31][(l>>5)*8+i] for both operands; k-layout
// permutations cancel, result is symmetric). Each lane: 2x float4 load -> 8 squares
// -> 8 cvt -> 1 MFMA. No barriers in the loop; pure HBM streaming (~21 us floor).
// Precision: gram ~= K/9 ~= 1820 >> margin 0.1, bf16 is safely sufficient.

#define MARGIN 0.1f

constexpr int B_ = 64;
constexpr int M_ = 32;
constexpr int K_ = 16384;
constexpr int NC = 16;           // k-chunks per batch -> grid 1024 = 4 blocks/CU
constexpr int KC = K_ / NC;      // 1024; each of 4 waves takes 256 k = 16 MFMA steps

typedef __attribute__((ext_vector_type(8))) short bf16x8;
typedef __attribute__((ext_vector_type(16))) float f32x16;

static __device__ __forceinline__ short f2bf(float f) {
  return __builtin_bit_cast(short, __float2bfloat16(f));
}

__global__ __launch_bounds__(256) void gram_mfma(const float* __restrict__ A,
                                                 float* __restrict__ ws_g) {
  const int tid  = threadIdx.x;
  const int w    = tid >> 6;       // wave 0..3
  const int lane = tid & 63;
  const int b    = blockIdx.x >> 4;
  const int c    = blockIdx.x & (NC - 1);
  const int row  = lane & 31;      // gram row/col this lane feeds (A and B roles)
  const int kh   = lane >> 5;      // k-half within a 16-k MFMA step

  // lane's stream: row (lane&31) of batch b, k in [c*KC + w*256, +256), 8 elems/step
  const size_t ebase = (size_t)(b * M_ + row) * K_ + (size_t)c * KC + w * (KC / 4) + kh * 8;
  const float4* p = reinterpret_cast<const float4*>(A + ebase);

  f32x16 acc = {};

#pragma unroll
  for (int s = 0; s < 16; ++s) {
    const float4 f0 = p[s * 4 + 0];   // k advances 16 per step = 4 float4
    const float4 f1 = p[s * 4 + 1];
    bf16x8 frag;
    frag[0] = f2bf(f0.x * f0.x);
    frag[1] = f2bf(f0.y * f0.y);
    frag[2] = f2bf(f0.z * f0.z);
    frag[3] = f2bf(f0.w * f0.w);
    frag[4] = f2bf(f1.x * f1.x);
    frag[5] = f2bf(f1.y * f1.y);
    frag[6] = f2bf(f1.z * f1.z);
    frag[7] = f2bf(f1.w * f1.w);
    acc = __builtin_amdgcn_mfma_f32_32x32x16_bf16(frag, frag, acc, 0, 0, 0);
  }

  // Cross-wave k-reduce via LDS (only sync in the kernel).
  // C/D layout (HW-verified m74/m101): col = lane&31, row = (r&3) + 8*(r>>2) + 4*(lane>>5)
  __shared__ float red[4][M_ * M_];  // 16 KiB
#pragma unroll
  for (int r = 0; r < 16; ++r) {
    const int rr = (r & 3) + 8 * (r >> 2) + 4 * kh;
    red[w][rr * 32 + row] = acc[r];  // banks = row -> 2-way (free)
  }
  __syncthreads();

  const float4* R4 = reinterpret_cast<const float4*>(&red[0][0]);
  const float4 s0 = R4[tid];
  const float4 s1 = R4[256 + tid];
  const float4 s2 = R4[512 + tid];
  const float4 s3 = R4[768 + tid];
  float4 o;
  o.x = s0.x + s1.x + s2.x + s3.x;
  o.y = s0.y + s1.y + s2.y + s3.y;
  o.z = s0.z + s1.z + s2.z + s3.z;
  o.w = s0.w + s1.w + s2.w + s3.w;
  reinterpret_cast<float4*>(ws_g)[(size_t)blockIdx.x * 256 + tid] = o;
}

// Kernel 2: per-batch -> sum chunk partials, relu margin, strict upper triangle.
__global__ __launch_bounds__(256) void reduce_batch(const float* __restrict__ ws_g,
                                                    float* __restrict__ ws_b) {
  const int b   = blockIdx.x;
  const int tid = threadIdx.x;
  const float4* G4 = reinterpret_cast<const float4*>(ws_g);

  float4 s = make_float4(0.f, 0.f, 0.f, 0.f);
#pragma unroll
  for (int c = 0; c < NC; ++c) {
    const float4 t = G4[((size_t)(b * NC + c)) * 256 + tid];
    s.x += t.x; s.y += t.y; s.z += t.z; s.w += t.w;
  }
  const float gv[4] = {s.x, s.y, s.z, s.w};
  float local = 0.f;
#pragma unroll
  for (int e = 0; e < 4; ++e) {
    const int idx = tid * 4 + e;
    const int ii = idx >> 5;
    const int jj = idx & 31;
    if (jj > ii) local += fmaxf(MARGIN - gv[e], 0.0f);
  }

  float vv = local;
#pragma unroll
  for (int off = 32; off > 0; off >>= 1) vv += __shfl_down(vv, off);
  __shared__ float red[4];
  if ((tid & 63) == 0) red[tid >> 6] = vv;
  __syncthreads();
  if (tid == 0) ws_b[b] = (red[0] + red[1] + red[2] + red[3]) * (1.0f / 496.0f);
}

// Kernel 3: mean over batches.
__global__ void final_mean(const float* __restrict__ ws_b, float* __restrict__ out) {
  float v = ws_b[threadIdx.x];  // 64 threads
#pragma unroll
  for (int off = 32; off > 0; off >>= 1) v += __shfl_down(v, off);
  if (threadIdx.x == 0) out[0] = v * (1.0f / 64.0f);
}

extern "C" void kernel_launch(void* const* d_in, const int* in_sizes, int n_in,
                              void* d_out, int out_size, void* d_ws, size_t ws_size,
                              hipStream_t stream) {
  const float* A = reinterpret_cast<const float*>(d_in[0]);
  float* out = reinterpret_cast<float*>(d_out);

  // ws: [1024 blocks][1024 floats] partial grams (4 MiB) + [64] per-batch losses
  float* ws_g = reinterpret_cast<float*>(d_ws);
  float* ws_b = ws_g + (size_t)B_ * NC * M_ * M_;

  gram_mfma<<<B_ * NC, 256, 0, stream>>>(A, ws_g);
  reduce_batch<<<B_, 256, 0, stream>>>(ws_g, ws_b);
  final_mean<<<1, 64, 0, stream>>>(ws_b, out);
}